// Round 3
// baseline (371.591 us; speedup 1.0000x reference)
//
#include <hip/hip_runtime.h>
#include <hip/hip_bf16.h>

#define NPOS 6272          // 8*28*28
#define NT   98            // NPOS/64
#define CIN  256
#define CR   32
#define BATCH 2
// QSCALE * log2(e): scores come out in log2 units -> softmax uses raw exp2
#define QS2  0.25503371989518595f

// ---------------------------------------------------------------------------
// Kernel 1: Q/K/V projections, fine-grained split for occupancy.
// grid (NT, B, 12): z -> (mat = z>>2, r-quarter = z&3); wave g handles 2 rows.
// 4704... -> 98*2*12=2352 blocks * 4 waves = 9408 waves (~37/CU).
// Q layout [B][32][N]; K,V layout [B][N][32].
// ---------------------------------------------------------------------------
__global__ __launch_bounds__(256) void qkv_kernel(
    const float* __restrict__ x, const float* __restrict__ qw,
    const float* __restrict__ kw, const float* __restrict__ vw,
    float* __restrict__ Q, float* __restrict__ K, float* __restrict__ V)
{
    const int b   = blockIdx.y;
    const int z   = blockIdx.z;
    const int mat = z >> 2;
    const int nl  = threadIdx.x & 63;
    const int n   = blockIdx.x * 64 + nl;
    const int g   = __builtin_amdgcn_readfirstlane(threadIdx.x >> 6); // 0..3
    const int r0  = (z & 3) * 8 + g * 2;          // wave-uniform row pair
    const float* w  = (mat == 0) ? qw : (mat == 1) ? kw : vw;
    const float* w0 = w + r0 * CIN;
    const float* w1 = w + (r0 + 1) * CIN;
    const float* xb = x + (size_t)b * CIN * NPOS + n;

    float a0 = 0.f, a1 = 0.f;
    for (int c = 0; c < CIN; c += 4) {            // 4-deep load pipelining
        float x0 = xb[(size_t)(c + 0) * NPOS];
        float x1 = xb[(size_t)(c + 1) * NPOS];
        float x2 = xb[(size_t)(c + 2) * NPOS];
        float x3 = xb[(size_t)(c + 3) * NPOS];
        a0 += w0[c] * x0;  a1 += w1[c] * x0;
        a0 += w0[c+1] * x1; a1 += w1[c+1] * x1;
        a0 += w0[c+2] * x2; a1 += w1[c+2] * x2;
        a0 += w0[c+3] * x3; a1 += w1[c+3] * x3;
    }
    if (mat == 0) {
        Q[((size_t)b * CR + r0)     * NPOS + n] = a0 * QS2;
        Q[((size_t)b * CR + r0 + 1) * NPOS + n] = a1 * QS2;
    } else {
        float* dst = (mat == 1) ? K : V;
        dst[((size_t)b * NPOS + n) * CR + r0]     = a0;
        dst[((size_t)b * NPOS + n) * CR + r0 + 1] = a1;
    }
}

// ---------------------------------------------------------------------------
// Kernel 2: flash attention with key-split (scores already in log2 units).
// 1 block = 1 wave = 64 queries; blockIdx.y = key split s; blockIdx.z = batch.
// __launch_bounds__(64, 4): min 4 waves/EU -> VGPR cap 128 -> NO SPILLS
// (round-2 had VGPR_Count=48 with ~100 live floats -> scratch thrash).
// ---------------------------------------------------------------------------
__global__ __launch_bounds__(64, 4) void attn_kernel(
    const float* __restrict__ Q, const float* __restrict__ K,
    const float* __restrict__ V, __hip_bfloat16* __restrict__ Opart,
    float* __restrict__ Mpart, float* __restrict__ Lpart, int kps)
{
    const int b = blockIdx.z;
    const int s = blockIdx.y;
    const int n = blockIdx.x * 64 + threadIdx.x;

    const float* Qb = Q + (size_t)b * CR * NPOS + n;
    const float* Kb = K + (size_t)b * NPOS * CR;
    const float* Vb = V + (size_t)b * NPOS * CR;

    float q[CR];
#pragma unroll
    for (int r = 0; r < CR; ++r) q[r] = Qb[(size_t)r * NPOS];
    float o[CR];
#pragma unroll
    for (int r = 0; r < CR; ++r) o[r] = 0.f;
    float m = -1e30f, l = 0.f;

    const int j0 = s * kps;
    for (int jc = 0; jc < kps; jc += 8) {        // kps % 8 == 0 guaranteed
        float sc[8];
#pragma unroll
        for (int jj = 0; jj < 8; ++jj) {
            const float* kr = Kb + (size_t)(j0 + jc + jj) * CR;  // uniform row
            float a0 = 0.f, a1 = 0.f, a2 = 0.f, a3 = 0.f;
#pragma unroll
            for (int r = 0; r < CR; r += 4) {
                a0 += q[r]     * kr[r];
                a1 += q[r + 1] * kr[r + 1];
                a2 += q[r + 2] * kr[r + 2];
                a3 += q[r + 3] * kr[r + 3];
            }
            sc[jj] = (a0 + a1) + (a2 + a3);
        }
        float cm = sc[0];
#pragma unroll
        for (int jj = 1; jj < 8; ++jj) cm = fmaxf(cm, sc[jj]);
        float mn    = fmaxf(m, cm);
        float alpha = __builtin_amdgcn_exp2f(m - mn);
        l *= alpha;
#pragma unroll
        for (int r = 0; r < CR; ++r) o[r] *= alpha;
#pragma unroll
        for (int jj = 0; jj < 8; ++jj) {
            float p = __builtin_amdgcn_exp2f(sc[jj] - mn);
            l += p;
            const float* vr = Vb + (size_t)(j0 + jc + jj) * CR;  // uniform row
#pragma unroll
            for (int r = 0; r < CR; ++r) o[r] += p * vr[r];
        }
        m = mn;
    }

    __hip_bfloat16* Ob = Opart + (size_t)(s * BATCH + b) * CR * NPOS + n;
#pragma unroll
    for (int r = 0; r < CR; ++r) Ob[(size_t)r * NPOS] = __float2bfloat16(o[r]);
    Mpart[(size_t)(s * BATCH + b) * NPOS + n] = m;
    Lpart[(size_t)(s * BATCH + b) * NPOS + n] = l;
}

// ---------------------------------------------------------------------------
// Kernel 3: merge key-splits (log-sum-exp combine) -> Omrg [B][32][N] fp32.
// grid (NT, B, 8), block 256: wave handles r = z*4 + g (one row).
// 98*2*8=1568 blocks * 4 waves = 6272 waves (~24/CU); split weights
// recomputed per wave (no LDS / barriers).
// ---------------------------------------------------------------------------
__global__ __launch_bounds__(256) void merge_kernel(
    const __hip_bfloat16* __restrict__ Opart, const float* __restrict__ Mpart,
    const float* __restrict__ Lpart, float* __restrict__ Omrg, int S)
{
    const int b  = blockIdx.y;
    const int z  = blockIdx.z;
    const int nl = threadIdx.x & 63;
    const int n  = blockIdx.x * 64 + nl;
    const int g  = __builtin_amdgcn_readfirstlane(threadIdx.x >> 6);
    const int r  = z * 4 + g;

    float mg = -1e30f;
    for (int s = 0; s < S; ++s)
        mg = fmaxf(mg, Mpart[(size_t)(s * BATCH + b) * NPOS + n]);
    float lg = 0.f, acc = 0.f;
    for (int s = 0; s < S; ++s) {
        float ms = Mpart[(size_t)(s * BATCH + b) * NPOS + n];
        float w  = __builtin_amdgcn_exp2f(ms - mg);
        lg += w * Lpart[(size_t)(s * BATCH + b) * NPOS + n];
        acc += w * __bfloat162float(
            Opart[((size_t)(s * BATCH + b) * CR + r) * NPOS + n]);
    }
    Omrg[((size_t)b * CR + r) * NPOS + n] = acc / lg;
}

// ---------------------------------------------------------------------------
// Kernel 4: output projection + residual.
// grid (NT, B, 8), block 256: wave handles 8 channels c in [z*32+8g, +8).
// 6272 waves (~24/CU).
// ---------------------------------------------------------------------------
__global__ __launch_bounds__(256) void proj_kernel(
    const float* __restrict__ Omrg, const float* __restrict__ ow,
    const float* __restrict__ x, float* __restrict__ y)
{
    const int b  = blockIdx.y;
    const int z  = blockIdx.z;
    const int nl = threadIdx.x & 63;
    const int n  = blockIdx.x * 64 + nl;
    const int g  = __builtin_amdgcn_readfirstlane(threadIdx.x >> 6);

    float o[CR];
#pragma unroll
    for (int r = 0; r < CR; ++r)
        o[r] = Omrg[((size_t)b * CR + r) * NPOS + n];

    const float* xb = x + (size_t)b * CIN * NPOS + n;
    float*       yb = y + (size_t)b * CIN * NPOS + n;
    const int c0 = z * 32 + g * 8;
    for (int cc = 0; cc < 8; ++cc) {
        int c = c0 + cc;                          // wave-uniform
        float acc = xb[(size_t)c * NPOS];
#pragma unroll
        for (int r = 0; r < CR; ++r) acc += ow[c * CR + r] * o[r];
        yb[(size_t)c * NPOS] = acc;
    }
}

// ---------------------------------------------------------------------------
extern "C" void kernel_launch(void* const* d_in, const int* in_sizes, int n_in,
                              void* d_out, int out_size, void* d_ws, size_t ws_size,
                              hipStream_t stream)
{
    const float* x  = (const float*)d_in[0];
    const float* qw = (const float*)d_in[1];
    const float* kw = (const float*)d_in[2];
    const float* vw = (const float*)d_in[3];
    const float* ow = (const float*)d_in[4];
    float* out = (float*)d_out;

    const size_t qkvN = (size_t)BATCH * CR * NPOS;  // 401,408 elements
    // S candidates keep kps = NPOS/S a multiple of 8 (chunk loop).
    const int s_cand[6] = {28, 14, 7, 4, 2, 1};
    int S = 1;
    for (int i = 0; i < 6; ++i) {
        int Sc = s_cand[i];
        size_t need = (3 * qkvN + qkvN) * sizeof(float)               // Q,K,V,Omrg
                    + (size_t)Sc * qkvN * sizeof(__hip_bfloat16)      // Opart
                    + 2 * (size_t)Sc * BATCH * NPOS * sizeof(float);  // M,L
        if (need <= ws_size) { S = Sc; break; }
    }
    float* Q    = (float*)d_ws;
    float* K    = Q + qkvN;
    float* V    = K + qkvN;
    float* Omrg = V + qkvN;
    __hip_bfloat16* Op = (__hip_bfloat16*)(Omrg + qkvN);
    float* Mp = (float*)(Op + (size_t)S * qkvN);
    float* Lp = Mp + (size_t)S * BATCH * NPOS;
    const int kps = NPOS / S;

    qkv_kernel<<<dim3(NT, BATCH, 12), 256, 0, stream>>>(x, qw, kw, vw, Q, K, V);
    attn_kernel<<<dim3(NT, S, BATCH), 64, 0, stream>>>(Q, K, V, Op, Mp, Lp, kps);
    merge_kernel<<<dim3(NT, BATCH, 8), 256, 0, stream>>>(Op, Mp, Lp, Omrg, S);
    proj_kernel<<<dim3(NT, BATCH, 8), 256, 0, stream>>>(Omrg, ow, x, out);
}

// Round 5
// 179.515 us; speedup vs baseline: 2.0700x; 2.0700x over previous
//
#include <hip/hip_runtime.h>
#include <hip/hip_bf16.h>

#define NPOS 6272          // 8*28*28
#define NT   98            // NPOS/64
#define CIN  256
#define CR   32
#define BATCH 2
// QSCALE * log2(e): scores come out in log2 units -> softmax uses raw exp2
#define QS2  0.25503371989518595f

typedef short bf16x8s __attribute__((ext_vector_type(8)));  // 8 bf16 = 4 VGPR
typedef float f32x4   __attribute__((ext_vector_type(4)));
typedef unsigned short ushort_t;

__device__ __forceinline__ ushort_t f2bf(float f) {        // RNE fp32->bf16
    unsigned u = __builtin_bit_cast(unsigned, f);
    u += 0x7fff + ((u >> 16) & 1);
    return (ushort_t)(u >> 16);
}
__device__ __forceinline__ float bf2f(ushort_t h) {
    return __builtin_bit_cast(float, (unsigned)h << 16);
}

// ---------------------------------------------------------------------------
// Kernel 1: Q/K/V projections -> bf16 MFMA layouts, SPLIT precision for Q,K.
//   Qh,Ql,Kh,Kl : [B][N][32] bf16 (hi + RNE residual; S = QhKh+QlKh+QhKl
//                 recovers ~fp32 scores -> no softmax tie-flips)
//   Vt          : [B][32][N] bf16 (PV B-operand layout)
// grid (NT, B, 3); block 256 = 4 waves; wave g computes rows 8g..8g+7.
// ---------------------------------------------------------------------------
__global__ __launch_bounds__(256) void qkv_kernel(
    const float* __restrict__ x, const float* __restrict__ qw,
    const float* __restrict__ kw, const float* __restrict__ vw,
    ushort_t* __restrict__ Qh, ushort_t* __restrict__ Ql,
    ushort_t* __restrict__ Kh, ushort_t* __restrict__ Kl,
    ushort_t* __restrict__ Vt)
{
    const int b   = blockIdx.y;
    const int z   = blockIdx.z;
    const int nl  = threadIdx.x & 63;
    const int n   = blockIdx.x * 64 + nl;
    const int g   = __builtin_amdgcn_readfirstlane(threadIdx.x >> 6); // 0..3
    const float* w  = (z == 0) ? qw : (z == 1) ? kw : vw;
    const float* xb = x + (size_t)b * CIN * NPOS + n;

    float acc[8];
#pragma unroll
    for (int i = 0; i < 8; ++i) acc[i] = 0.f;
    for (int c = 0; c < CIN; c += 2) {
        float x0 = xb[(size_t)c * NPOS];
        float x1 = xb[(size_t)(c + 1) * NPOS];
#pragma unroll
        for (int i = 0; i < 8; ++i) {
            int r = g * 8 + i;                   // wave-uniform weight rows
            acc[i] += w[r * CIN + c] * x0;
            acc[i] += w[r * CIN + c + 1] * x1;
        }
    }
    if (z == 2) {                                // V -> transposed [32][N]
#pragma unroll
        for (int i = 0; i < 8; ++i)
            Vt[((size_t)b * CR + g * 8 + i) * NPOS + n] = f2bf(acc[i]);
    } else {
        ushort_t* dh = (z == 0) ? Qh : Kh;
        ushort_t* dl = (z == 0) ? Ql : Kl;
        float s = (z == 0) ? QS2 : 1.0f;         // fold softmax scale into Q
        bf16x8s fh, fl;
#pragma unroll
        for (int i = 0; i < 8; ++i) {
            float v = acc[i] * s;
            ushort_t h = f2bf(v);
            fh[i] = (short)h;
            fl[i] = (short)f2bf(v - bf2f(h));    // residual
        }
        size_t off = ((size_t)b * NPOS + n) * CR + g * 8;
        *(bf16x8s*)(dh + off) = fh;
        *(bf16x8s*)(dl + off) = fl;
    }
}

// ---------------------------------------------------------------------------
// Kernel 2: MFMA flash attention, split-bf16 scores, fp32 accum, key-split.
// grid (49, S, B); block 256 = 4 waves; wave w owns 32 queries (2 q-halves).
// Per 32-key iter: 12 score MFMAs (3-term split) -> online softmax in
// C-layout -> P via per-wave LDS C->A transform -> 4 PV MFMAs.
// l kept as PER-LANE partials (reduced once in epilogue).
// ---------------------------------------------------------------------------
__global__ __launch_bounds__(256, 4) void attn_kernel(
    const ushort_t* __restrict__ Qh, const ushort_t* __restrict__ Ql,
    const ushort_t* __restrict__ Kh, const ushort_t* __restrict__ Kl,
    const ushort_t* __restrict__ Vt, ushort_t* __restrict__ Opart,
    float* __restrict__ Mp, float* __restrict__ Lp, int iters)
{
    __shared__ __align__(16) ushort_t pbuf[4 * 2 * 512]; // [wave][half][16][32]

    const int lane = threadIdx.x & 63;
    const int wv   = threadIdx.x >> 6;           // 0..3
    const int col  = lane & 15;
    const int quad = lane >> 4;                  // 0..3
    const int b    = blockIdx.z;
    const int s    = blockIdx.y;
    const int qw0  = blockIdx.x * 128 + wv * 32;

    const ushort_t* Qhb = Qh + (size_t)b * NPOS * CR;
    const ushort_t* Qlb = Ql + (size_t)b * NPOS * CR;
    const ushort_t* Khb = Kh + (size_t)b * NPOS * CR;
    const ushort_t* Klb = Kl + (size_t)b * NPOS * CR;
    const ushort_t* Vtb = Vt + (size_t)b * CR * NPOS;

    // Q A-fragments (half h: query qw0+16h+col, dims quad*8..+7), hi & lo
    bf16x8s qah[2], qal[2];
    qah[0] = *(const bf16x8s*)(Qhb + (size_t)(qw0 + col) * CR + quad * 8);
    qah[1] = *(const bf16x8s*)(Qhb + (size_t)(qw0 + 16 + col) * CR + quad * 8);
    qal[0] = *(const bf16x8s*)(Qlb + (size_t)(qw0 + col) * CR + quad * 8);
    qal[1] = *(const bf16x8s*)(Qlb + (size_t)(qw0 + 16 + col) * CR + quad * 8);

    f32x4 oc[2][2];                              // [qhalf][chhalf]
#pragma unroll
    for (int h = 0; h < 2; ++h)
#pragma unroll
        for (int c = 0; c < 2; ++c)
#pragma unroll
            for (int r = 0; r < 4; ++r) oc[h][c][r] = 0.f;
    float mrow[2][4], lrow[2][4];                // lrow = per-lane partial!
#pragma unroll
    for (int h = 0; h < 2; ++h)
#pragma unroll
        for (int r = 0; r < 4; ++r) { mrow[h][r] = -1e30f; lrow[h][r] = 0.f; }

    for (int it = 0; it < iters; ++it) {
        const int j0 = (s * iters + it) * 32;
        bf16x8s kh0 = *(const bf16x8s*)(Khb + (size_t)(j0 + col) * CR + quad * 8);
        bf16x8s kh1 = *(const bf16x8s*)(Khb + (size_t)(j0 + 16 + col) * CR + quad * 8);
        bf16x8s kl0 = *(const bf16x8s*)(Klb + (size_t)(j0 + col) * CR + quad * 8);
        bf16x8s kl1 = *(const bf16x8s*)(Klb + (size_t)(j0 + 16 + col) * CR + quad * 8);
        bf16x8s vb0 = *(const bf16x8s*)(Vtb + (size_t)col * NPOS + j0 + quad * 8);
        bf16x8s vb1 = *(const bf16x8s*)(Vtb + (size_t)(16 + col) * NPOS + j0 + quad * 8);

        f32x4 z4; z4[0] = 0.f; z4[1] = 0.f; z4[2] = 0.f; z4[3] = 0.f;
        f32x4 sc[2][2];
#pragma unroll
        for (int h = 0; h < 2; ++h) {
            sc[h][0] = __builtin_amdgcn_mfma_f32_16x16x32_bf16(qah[h], kl0, z4, 0, 0, 0);
            sc[h][0] = __builtin_amdgcn_mfma_f32_16x16x32_bf16(qal[h], kh0, sc[h][0], 0, 0, 0);
            sc[h][0] = __builtin_amdgcn_mfma_f32_16x16x32_bf16(qah[h], kh0, sc[h][0], 0, 0, 0);
            sc[h][1] = __builtin_amdgcn_mfma_f32_16x16x32_bf16(qah[h], kl1, z4, 0, 0, 0);
            sc[h][1] = __builtin_amdgcn_mfma_f32_16x16x32_bf16(qal[h], kh1, sc[h][1], 0, 0, 0);
            sc[h][1] = __builtin_amdgcn_mfma_f32_16x16x32_bf16(qah[h], kh1, sc[h][1], 0, 0, 0);
        }

#pragma unroll
        for (int h = 0; h < 2; ++h) {
#pragma unroll
            for (int r = 0; r < 4; ++r) {
                // row max over 32 keys (per-lane pair max + 16-lane butterfly)
                float v = fmaxf(sc[h][0][r], sc[h][1][r]);
                v = fmaxf(v, __shfl_xor(v, 1));
                v = fmaxf(v, __shfl_xor(v, 2));
                v = fmaxf(v, __shfl_xor(v, 4));
                v = fmaxf(v, __shfl_xor(v, 8));
                float mo = mrow[h][r];
                float mn = fmaxf(mo, v);
                float al = __builtin_amdgcn_exp2f(mo - mn);
                float p0 = __builtin_amdgcn_exp2f(sc[h][0][r] - mn);
                float p1 = __builtin_amdgcn_exp2f(sc[h][1][r] - mn);
                mrow[h][r] = mn;
                lrow[h][r] = lrow[h][r] * al + (p0 + p1);  // per-lane partial
                oc[h][0][r] *= al;
                oc[h][1][r] *= al;
                const int row = quad * 4 + r;
                pbuf[(wv * 2 + h) * 512 + row * 32 + col]      = f2bf(p0);
                pbuf[(wv * 2 + h) * 512 + row * 32 + col + 16] = f2bf(p1);
            }
        }
        // P A-frags: m=col, k=quad*8+j (contiguous 16B -> ds_read_b128)
        bf16x8s pa0 = *(bf16x8s*)(&pbuf[(wv * 2 + 0) * 512 + col * 32 + quad * 8]);
        bf16x8s pa1 = *(bf16x8s*)(&pbuf[(wv * 2 + 1) * 512 + col * 32 + quad * 8]);
        oc[0][0] = __builtin_amdgcn_mfma_f32_16x16x32_bf16(pa0, vb0, oc[0][0], 0, 0, 0);
        oc[0][1] = __builtin_amdgcn_mfma_f32_16x16x32_bf16(pa0, vb1, oc[0][1], 0, 0, 0);
        oc[1][0] = __builtin_amdgcn_mfma_f32_16x16x32_bf16(pa1, vb0, oc[1][0], 0, 0, 0);
        oc[1][1] = __builtin_amdgcn_mfma_f32_16x16x32_bf16(pa1, vb1, oc[1][1], 0, 0, 0);
    }

    // Reduce the per-lane l partials across the 16 cols of each row.
#pragma unroll
    for (int h = 0; h < 2; ++h)
#pragma unroll
        for (int r = 0; r < 4; ++r) {
            float l = lrow[h][r];
            l += __shfl_xor(l, 1);
            l += __shfl_xor(l, 2);
            l += __shfl_xor(l, 4);
            l += __shfl_xor(l, 8);
            lrow[h][r] = l;
        }

    // Epilogue: Opart[sb][q][32ch] bf16
    const size_t sb = (size_t)(s * BATCH + b);
    ushort_t* Ob = Opart + sb * NPOS * CR;
#pragma unroll
    for (int h = 0; h < 2; ++h)
#pragma unroll
        for (int c = 0; c < 2; ++c)
#pragma unroll
            for (int r = 0; r < 4; ++r) {
                int q  = qw0 + h * 16 + quad * 4 + r;
                int ch = c * 16 + col;
                Ob[(size_t)q * CR + ch] = f2bf(oc[h][c][r]);
            }
    if (col == 0) {                              // lanes 0,16,32,48 own rows
#pragma unroll
        for (int h = 0; h < 2; ++h)
#pragma unroll
            for (int r = 0; r < 4; ++r) {
                int q = qw0 + h * 16 + quad * 4 + r;
                Mp[sb * NPOS + q] = mrow[h][r];
                Lp[sb * NPOS + q] = lrow[h][r];
            }
    }
}

// ---------------------------------------------------------------------------
// Kernel 3: merge key-splits (log-sum-exp) -> Omrg [B][32][N] fp32.
// grid (NT, B, 8), block 256: wave g handles ch r = z*4+g.
// ---------------------------------------------------------------------------
__global__ __launch_bounds__(256) void merge_kernel(
    const ushort_t* __restrict__ Opart, const float* __restrict__ Mp,
    const float* __restrict__ Lp, float* __restrict__ Omrg, int S)
{
    const int b  = blockIdx.y;
    const int z  = blockIdx.z;
    const int nl = threadIdx.x & 63;
    const int n  = blockIdx.x * 64 + nl;
    const int g  = __builtin_amdgcn_readfirstlane(threadIdx.x >> 6);
    const int r  = z * 4 + g;

    float mg = -1e30f;
    for (int s = 0; s < S; ++s)
        mg = fmaxf(mg, Mp[(size_t)(s * BATCH + b) * NPOS + n]);
    float lg = 0.f, acc = 0.f;
    for (int s = 0; s < S; ++s) {
        size_t sb = (size_t)(s * BATCH + b);
        float w = __builtin_amdgcn_exp2f(Mp[sb * NPOS + n] - mg);
        lg  += w * Lp[sb * NPOS + n];
        acc += w * bf2f(Opart[(sb * NPOS + n) * CR + r]);
    }
    Omrg[((size_t)b * CR + r) * NPOS + n] = acc / lg;
}

// ---------------------------------------------------------------------------
// Kernel 4: output projection + residual.
// grid (NT, B, 8), block 256: wave g handles 8 channels c in [z*32+8g, +8).
// ---------------------------------------------------------------------------
__global__ __launch_bounds__(256) void proj_kernel(
    const float* __restrict__ Omrg, const float* __restrict__ ow,
    const float* __restrict__ x, float* __restrict__ y)
{
    const int b  = blockIdx.y;
    const int z  = blockIdx.z;
    const int nl = threadIdx.x & 63;
    const int n  = blockIdx.x * 64 + nl;
    const int g  = __builtin_amdgcn_readfirstlane(threadIdx.x >> 6);

    float o[CR];
#pragma unroll
    for (int r = 0; r < CR; ++r)
        o[r] = Omrg[((size_t)b * CR + r) * NPOS + n];

    const float* xb = x + (size_t)b * CIN * NPOS + n;
    float*       yb = y + (size_t)b * CIN * NPOS + n;
    const int c0 = z * 32 + g * 8;
    for (int cc = 0; cc < 8; ++cc) {
        int c = c0 + cc;                          // wave-uniform
        float acc = xb[(size_t)c * NPOS];
#pragma unroll
        for (int r = 0; r < CR; ++r) acc += ow[c * CR + r] * o[r];
        yb[(size_t)c * NPOS] = acc;
    }
}

// ---------------------------------------------------------------------------
extern "C" void kernel_launch(void* const* d_in, const int* in_sizes, int n_in,
                              void* d_out, int out_size, void* d_ws, size_t ws_size,
                              hipStream_t stream)
{
    const float* x  = (const float*)d_in[0];
    const float* qw = (const float*)d_in[1];
    const float* kw = (const float*)d_in[2];
    const float* vw = (const float*)d_in[3];
    const float* ow = (const float*)d_in[4];
    float* out = (float*)d_out;

    const size_t qkvN = (size_t)BATCH * CR * NPOS;   // 401,408 elements
    // S must divide 196 (=6272/32) so every split is whole 32-key iters.
    const int s_cand[5] = {14, 7, 4, 2, 1};
    int S = 1;
    for (int i = 0; i < 5; ++i) {
        int Sc = s_cand[i];
        size_t need = 5 * qkvN * sizeof(ushort_t)            // Qh,Ql,Kh,Kl,Vt
                    + qkvN * sizeof(float)                   // Omrg
                    + (size_t)Sc * qkvN * sizeof(ushort_t)   // Opart
                    + 2 * (size_t)Sc * BATCH * NPOS * sizeof(float); // M,L
        if (need <= ws_size) { S = Sc; break; }
    }
    ushort_t* Qh = (ushort_t*)d_ws;
    ushort_t* Ql = Qh + qkvN;
    ushort_t* Kh = Ql + qkvN;
    ushort_t* Kl = Kh + qkvN;
    ushort_t* Vt = Kl + qkvN;
    float* Omrg  = (float*)(Vt + qkvN);
    ushort_t* Op = (ushort_t*)(Omrg + qkvN);
    float* Mp    = (float*)(Op + (size_t)S * qkvN);
    float* Lp    = Mp + (size_t)S * BATCH * NPOS;
    const int iters = 196 / S;

    qkv_kernel<<<dim3(NT, BATCH, 3), 256, 0, stream>>>(x, qw, kw, vw,
                                                       Qh, Ql, Kh, Kl, Vt);
    attn_kernel<<<dim3(49, S, BATCH), 256, 0, stream>>>(Qh, Ql, Kh, Kl, Vt,
                                                        Op, Mp, Lp, iters);
    merge_kernel<<<dim3(NT, BATCH, 8), 256, 0, stream>>>(Op, Mp, Lp, Omrg, S);
    proj_kernel<<<dim3(NT, BATCH, 8), 256, 0, stream>>>(Omrg, ow, x, out);
}

// Round 6
// 169.384 us; speedup vs baseline: 2.1938x; 1.0598x over previous
//
#include <hip/hip_runtime.h>
#include <hip/hip_bf16.h>

#define NPOS 6272          // 8*28*28
#define NT   98            // NPOS/64
#define CIN  256
#define CR   32
#define BATCH 2
// QSCALE * log2(e): scores come out in log2 units -> softmax uses raw exp2
#define QS2  0.25503371989518595f

typedef short bf16x8s __attribute__((ext_vector_type(8)));  // 8 bf16 = 4 VGPR
typedef float f32x4   __attribute__((ext_vector_type(4)));
typedef unsigned short ushort_t;

__device__ __forceinline__ ushort_t f2bf(float f) {        // RNE fp32->bf16
    unsigned u = __builtin_bit_cast(unsigned, f);
    u += 0x7fff + ((u >> 16) & 1);
    return (ushort_t)(u >> 16);
}
__device__ __forceinline__ float bf2f(ushort_t h) {
    return __builtin_bit_cast(float, (unsigned)h << 16);
}

// ---------------------------------------------------------------------------
// Kernel 1: Q/K/V projections -> bf16 MFMA layouts, SPLIT precision for Q,K.
//   Qh,Ql,Kh,Kl : [B][N][32] bf16 (hi + RNE residual)
//   Vt          : [B][32][N] bf16 (PV B-operand layout)
// grid (NT, B, 3); block 256 = 4 waves; wave g computes rows 8g..8g+7.
// ---------------------------------------------------------------------------
__global__ __launch_bounds__(256) void qkv_kernel(
    const float* __restrict__ x, const float* __restrict__ qw,
    const float* __restrict__ kw, const float* __restrict__ vw,
    ushort_t* __restrict__ Qh, ushort_t* __restrict__ Ql,
    ushort_t* __restrict__ Kh, ushort_t* __restrict__ Kl,
    ushort_t* __restrict__ Vt)
{
    const int b   = blockIdx.y;
    const int z   = blockIdx.z;
    const int nl  = threadIdx.x & 63;
    const int n   = blockIdx.x * 64 + nl;
    const int g   = __builtin_amdgcn_readfirstlane(threadIdx.x >> 6); // 0..3
    const float* w  = (z == 0) ? qw : (z == 1) ? kw : vw;
    const float* xb = x + (size_t)b * CIN * NPOS + n;

    float acc[8];
#pragma unroll
    for (int i = 0; i < 8; ++i) acc[i] = 0.f;
    for (int c = 0; c < CIN; c += 2) {
        float x0 = xb[(size_t)c * NPOS];
        float x1 = xb[(size_t)(c + 1) * NPOS];
#pragma unroll
        for (int i = 0; i < 8; ++i) {
            int r = g * 8 + i;                   // wave-uniform weight rows
            acc[i] += w[r * CIN + c] * x0;
            acc[i] += w[r * CIN + c + 1] * x1;
        }
    }
    if (z == 2) {                                // V -> transposed [32][N]
#pragma unroll
        for (int i = 0; i < 8; ++i)
            Vt[((size_t)b * CR + g * 8 + i) * NPOS + n] = f2bf(acc[i]);
    } else {
        ushort_t* dh = (z == 0) ? Qh : Kh;
        ushort_t* dl = (z == 0) ? Ql : Kl;
        float s = (z == 0) ? QS2 : 1.0f;         // fold softmax scale into Q
        bf16x8s fh, fl;
#pragma unroll
        for (int i = 0; i < 8; ++i) {
            float v = acc[i] * s;
            ushort_t h = f2bf(v);
            fh[i] = (short)h;
            fl[i] = (short)f2bf(v - bf2f(h));    // residual
        }
        size_t off = ((size_t)b * NPOS + n) * CR + g * 8;
        *(bf16x8s*)(dh + off) = fh;
        *(bf16x8s*)(dl + off) = fl;
    }
}

// ---------------------------------------------------------------------------
// Kernel 2: MFMA flash attention, split-bf16 scores, 64 keys/iter.
// grid (196, S, B); block 64 = 1 wave owning 32 queries (2 q-halves).
// Per iter: 24 score MFMAs (3-term split x 4 kfrags x 2 halves, h-sequential
// to cap VGPRs) -> online softmax -> P via XOR-swizzled LDS (C->A transform,
// conflicts ~2-way) -> 8 PV MFMAs. Epilogue transposes O through LDS so
// Opart is [sb][ch][n] (merge reads coalesced). Per-wave LDS, no barriers.
// ---------------------------------------------------------------------------
__global__ __launch_bounds__(64, 4) void attn_kernel(
    const ushort_t* __restrict__ Qh, const ushort_t* __restrict__ Ql,
    const ushort_t* __restrict__ Kh, const ushort_t* __restrict__ Kl,
    const ushort_t* __restrict__ Vt, ushort_t* __restrict__ Opart,
    float* __restrict__ Mp, float* __restrict__ Lp, int iters)
{
    __shared__ __align__(16) ushort_t pbuf[2048];  // 4KB: P [2h][16q][64k] swz

    const int lane = threadIdx.x;
    const int col  = lane & 15;
    const int quad = lane >> 4;                  // 0..3
    const int b    = blockIdx.z;
    const int s    = blockIdx.y;
    const int qw0  = blockIdx.x * 32;

    const ushort_t* Qhb = Qh + (size_t)b * NPOS * CR;
    const ushort_t* Qlb = Ql + (size_t)b * NPOS * CR;
    const ushort_t* Khb = Kh + (size_t)b * NPOS * CR;
    const ushort_t* Klb = Kl + (size_t)b * NPOS * CR;
    const ushort_t* Vtb = Vt + (size_t)b * CR * NPOS;

    bf16x8s qah[2], qal[2];
    qah[0] = *(const bf16x8s*)(Qhb + (size_t)(qw0 + col) * CR + quad * 8);
    qah[1] = *(const bf16x8s*)(Qhb + (size_t)(qw0 + 16 + col) * CR + quad * 8);
    qal[0] = *(const bf16x8s*)(Qlb + (size_t)(qw0 + col) * CR + quad * 8);
    qal[1] = *(const bf16x8s*)(Qlb + (size_t)(qw0 + 16 + col) * CR + quad * 8);

    f32x4 oc[2][2];                              // [qhalf][chhalf]
#pragma unroll
    for (int h = 0; h < 2; ++h)
#pragma unroll
        for (int c = 0; c < 2; ++c)
#pragma unroll
            for (int r = 0; r < 4; ++r) oc[h][c][r] = 0.f;
    float mrow[2][4], lrow[2][4];                // per-lane l partials
#pragma unroll
    for (int h = 0; h < 2; ++h)
#pragma unroll
        for (int r = 0; r < 4; ++r) { mrow[h][r] = -1e30f; lrow[h][r] = 0.f; }

    for (int it = 0; it < iters; ++it) {
        const int j0 = (s * iters + it) * 64;
        bf16x8s kh[4], kl[4], vb[2][2];
#pragma unroll
        for (int kf = 0; kf < 4; ++kf) {
            kh[kf] = *(const bf16x8s*)(Khb + (size_t)(j0 + kf * 16 + col) * CR + quad * 8);
            kl[kf] = *(const bf16x8s*)(Klb + (size_t)(j0 + kf * 16 + col) * CR + quad * 8);
        }
#pragma unroll
        for (int k2 = 0; k2 < 2; ++k2)
#pragma unroll
            for (int c = 0; c < 2; ++c)
                vb[k2][c] = *(const bf16x8s*)(Vtb + (size_t)(c * 16 + col) * NPOS
                                              + j0 + k2 * 32 + quad * 8);

        f32x4 z4; z4[0] = 0.f; z4[1] = 0.f; z4[2] = 0.f; z4[3] = 0.f;
#pragma unroll
        for (int h = 0; h < 2; ++h) {            // h-sequential: sc[4] live only
            f32x4 sc[4];
#pragma unroll
            for (int kf = 0; kf < 4; ++kf) {
                sc[kf] = __builtin_amdgcn_mfma_f32_16x16x32_bf16(qah[h], kl[kf], z4, 0, 0, 0);
                sc[kf] = __builtin_amdgcn_mfma_f32_16x16x32_bf16(qal[h], kh[kf], sc[kf], 0, 0, 0);
                sc[kf] = __builtin_amdgcn_mfma_f32_16x16x32_bf16(qah[h], kh[kf], sc[kf], 0, 0, 0);
            }
#pragma unroll
            for (int r = 0; r < 4; ++r) {
                float v = fmaxf(fmaxf(sc[0][r], sc[1][r]),
                                fmaxf(sc[2][r], sc[3][r]));
                v = fmaxf(v, __shfl_xor(v, 1));
                v = fmaxf(v, __shfl_xor(v, 2));
                v = fmaxf(v, __shfl_xor(v, 4));
                v = fmaxf(v, __shfl_xor(v, 8));
                float mo = mrow[h][r];
                float mn = fmaxf(mo, v);
                float al = __builtin_amdgcn_exp2f(mo - mn);
                float p0 = __builtin_amdgcn_exp2f(sc[0][r] - mn);
                float p1 = __builtin_amdgcn_exp2f(sc[1][r] - mn);
                float p2 = __builtin_amdgcn_exp2f(sc[2][r] - mn);
                float p3 = __builtin_amdgcn_exp2f(sc[3][r] - mn);
                mrow[h][r] = mn;
                lrow[h][r] = lrow[h][r] * al + ((p0 + p1) + (p2 + p3));
                oc[h][0][r] *= al;
                oc[h][1][r] *= al;
                // XOR-swizzled P store: row=quad*4+r, kcol=kf*16+col
                // kgrp = kf*2 + (col>>3); swz low2 with quad (row>>2)
                const int base = h * 1024 + (quad * 4 + r) * 64 + (col & 7);
#pragma unroll
                for (int kf = 0; kf < 4; ++kf) {
                    int kgrp = kf * 2 + (col >> 3);
                    int g = (kgrp & 4) | ((kgrp & 3) ^ quad);
                    float p = (kf == 0) ? p0 : (kf == 1) ? p1 : (kf == 2) ? p2 : p3;
                    pbuf[base + g * 8] = f2bf(p);
                }
            }
        }
        // P A-frags: row=col, k=k2*32+quad*8+j -> kgrp=k2*4+quad, swz w/ col>>2
#pragma unroll
        for (int h = 0; h < 2; ++h) {
            bf16x8s pa[2];
#pragma unroll
            for (int k2 = 0; k2 < 2; ++k2) {
                int g = k2 * 4 + (quad ^ ((col >> 2) & 3));
                pa[k2] = *(bf16x8s*)(&pbuf[h * 1024 + col * 64 + g * 8]);
            }
            oc[h][0] = __builtin_amdgcn_mfma_f32_16x16x32_bf16(pa[0], vb[0][0], oc[h][0], 0, 0, 0);
            oc[h][0] = __builtin_amdgcn_mfma_f32_16x16x32_bf16(pa[1], vb[1][0], oc[h][0], 0, 0, 0);
            oc[h][1] = __builtin_amdgcn_mfma_f32_16x16x32_bf16(pa[0], vb[0][1], oc[h][1], 0, 0, 0);
            oc[h][1] = __builtin_amdgcn_mfma_f32_16x16x32_bf16(pa[1], vb[1][1], oc[h][1], 0, 0, 0);
        }
    }

    // Reduce per-lane l partials across the 16 cols of each row.
#pragma unroll
    for (int h = 0; h < 2; ++h)
#pragma unroll
        for (int r = 0; r < 4; ++r) {
            float l = lrow[h][r];
            l += __shfl_xor(l, 1);
            l += __shfl_xor(l, 2);
            l += __shfl_xor(l, 4);
            l += __shfl_xor(l, 8);
            lrow[h][r] = l;
        }

    const size_t sb = (size_t)(s * BATCH + b);

    // Transpose O through LDS -> Opart[sb][ch][n] (coalesced merge reads).
#pragma unroll
    for (int h = 0; h < 2; ++h)
#pragma unroll
        for (int c = 0; c < 2; ++c)
#pragma unroll
            for (int r = 0; r < 4; ++r)
                pbuf[(c * 16 + col) * 32 + h * 16 + quad * 4 + r] = f2bf(oc[h][c][r]);
    {
        const int q   = lane & 31;
        const int chg = lane >> 5;               // 0..1
        ushort_t* Ob = Opart + sb * CR * NPOS + qw0 + q;
#pragma unroll
        for (int i = 0; i < 16; ++i) {
            int ch = chg * 16 + i;
            Ob[(size_t)ch * NPOS] = pbuf[ch * 32 + q];
        }
    }
    if (col == 0) {                              // lanes 0,16,32,48 own rows
#pragma unroll
        for (int h = 0; h < 2; ++h)
#pragma unroll
            for (int r = 0; r < 4; ++r) {
                int q = qw0 + h * 16 + quad * 4 + r;
                Mp[sb * NPOS + q] = mrow[h][r];
                Lp[sb * NPOS + q] = lrow[h][r];
            }
    }
}

// ---------------------------------------------------------------------------
// Kernel 3: merge key-splits (log-sum-exp) -> Omrg [B][32][N] fp32.
// grid (NT, B, 8), block 256: wave g handles ch r = z*4+g.
// Opart is now [sb][ch][n] -> inner loads fully coalesced.
// ---------------------------------------------------------------------------
__global__ __launch_bounds__(256) void merge_kernel(
    const ushort_t* __restrict__ Opart, const float* __restrict__ Mp,
    const float* __restrict__ Lp, float* __restrict__ Omrg, int S)
{
    const int b  = blockIdx.y;
    const int z  = blockIdx.z;
    const int nl = threadIdx.x & 63;
    const int n  = blockIdx.x * 64 + nl;
    const int g  = __builtin_amdgcn_readfirstlane(threadIdx.x >> 6);
    const int r  = z * 4 + g;

    float mg = -1e30f;
    for (int s = 0; s < S; ++s)
        mg = fmaxf(mg, Mp[(size_t)(s * BATCH + b) * NPOS + n]);
    float lg = 0.f, acc = 0.f;
    for (int s = 0; s < S; ++s) {
        size_t sb = (size_t)(s * BATCH + b);
        float w = __builtin_amdgcn_exp2f(Mp[sb * NPOS + n] - mg);
        lg  += w * Lp[sb * NPOS + n];
        acc += w * bf2f(Opart[(sb * CR + r) * NPOS + n]);   // coalesced
    }
    Omrg[((size_t)b * CR + r) * NPOS + n] = acc / lg;
}

// ---------------------------------------------------------------------------
// Kernel 4: output projection + residual.
// grid (NT, B, 8), block 256: wave g handles 8 channels c in [z*32+8g, +8).
// ---------------------------------------------------------------------------
__global__ __launch_bounds__(256) void proj_kernel(
    const float* __restrict__ Omrg, const float* __restrict__ ow,
    const float* __restrict__ x, float* __restrict__ y)
{
    const int b  = blockIdx.y;
    const int z  = blockIdx.z;
    const int nl = threadIdx.x & 63;
    const int n  = blockIdx.x * 64 + nl;
    const int g  = __builtin_amdgcn_readfirstlane(threadIdx.x >> 6);

    float o[CR];
#pragma unroll
    for (int r = 0; r < CR; ++r)
        o[r] = Omrg[((size_t)b * CR + r) * NPOS + n];

    const float* xb = x + (size_t)b * CIN * NPOS + n;
    float*       yb = y + (size_t)b * CIN * NPOS + n;
    const int c0 = z * 32 + g * 8;
    for (int cc = 0; cc < 8; ++cc) {
        int c = c0 + cc;                          // wave-uniform
        float acc = xb[(size_t)c * NPOS];
#pragma unroll
        for (int r = 0; r < CR; ++r) acc += ow[c * CR + r] * o[r];
        yb[(size_t)c * NPOS] = acc;
    }
}

// ---------------------------------------------------------------------------
extern "C" void kernel_launch(void* const* d_in, const int* in_sizes, int n_in,
                              void* d_out, int out_size, void* d_ws, size_t ws_size,
                              hipStream_t stream)
{
    const float* x  = (const float*)d_in[0];
    const float* qw = (const float*)d_in[1];
    const float* kw = (const float*)d_in[2];
    const float* vw = (const float*)d_in[3];
    const float* ow = (const float*)d_in[4];
    float* out = (float*)d_out;

    const size_t qkvN = (size_t)BATCH * CR * NPOS;   // 401,408 elements
    // S must divide 98 (=6272/64) so every split is whole 64-key iters.
    const int s_cand[4] = {14, 7, 2, 1};
    int S = 1;
    for (int i = 0; i < 4; ++i) {
        int Sc = s_cand[i];
        size_t need = 5 * qkvN * sizeof(ushort_t)            // Qh,Ql,Kh,Kl,Vt
                    + qkvN * sizeof(float)                   // Omrg
                    + (size_t)Sc * qkvN * sizeof(ushort_t)   // Opart
                    + 2 * (size_t)Sc * BATCH * NPOS * sizeof(float); // M,L
        if (need <= ws_size) { S = Sc; break; }
    }
    ushort_t* Qh = (ushort_t*)d_ws;
    ushort_t* Ql = Qh + qkvN;
    ushort_t* Kh = Ql + qkvN;
    ushort_t* Kl = Kh + qkvN;
    ushort_t* Vt = Kl + qkvN;
    float* Omrg  = (float*)(Vt + qkvN);
    ushort_t* Op = (ushort_t*)(Omrg + qkvN);
    float* Mp    = (float*)(Op + (size_t)S * qkvN);
    float* Lp    = Mp + (size_t)S * BATCH * NPOS;
    const int iters = NPOS / (S * 64);

    qkv_kernel<<<dim3(NT, BATCH, 3), 256, 0, stream>>>(x, qw, kw, vw,
                                                       Qh, Ql, Kh, Kl, Vt);
    attn_kernel<<<dim3(196, S, BATCH), 64, 0, stream>>>(Qh, Ql, Kh, Kl, Vt,
                                                        Op, Mp, Lp, iters);
    merge_kernel<<<dim3(NT, BATCH, 8), 256, 0, stream>>>(Op, Mp, Lp, Omrg, S);
    proj_kernel<<<dim3(NT, BATCH, 8), 256, 0, stream>>>(Omrg, ow, x, out);
}

// Round 7
// 152.888 us; speedup vs baseline: 2.4305x; 1.1079x over previous
//
#include <hip/hip_runtime.h>
#include <hip/hip_bf16.h>

#define NPOS 6272          // 8*28*28
#define NT   98            // NPOS/64
#define CIN  256
#define CR   32
#define BATCH 2
// QSCALE * log2(e): scores come out in log2 units -> softmax uses raw exp2
#define QS2  0.25503371989518595f
#define PPITCH 72          // P^T LDS row pitch (shorts): 144B = 9*16 -> aligned,
                           // ~4 lanes/bank-pair on b64 writes (near-free)

typedef short bf16x8s __attribute__((ext_vector_type(8)));  // 8 bf16 = 4 VGPR
typedef short short4v __attribute__((ext_vector_type(4)));  // 4 bf16 = 8B
typedef float f32x4   __attribute__((ext_vector_type(4)));
typedef unsigned short ushort_t;

__device__ __forceinline__ ushort_t f2bf(float f) {        // RNE fp32->bf16
    unsigned u = __builtin_bit_cast(unsigned, f);
    u += 0x7fff + ((u >> 16) & 1);
    return (ushort_t)(u >> 16);
}
__device__ __forceinline__ float bf2f(ushort_t h) {
    return __builtin_bit_cast(float, (unsigned)h << 16);
}

// ---------------------------------------------------------------------------
// Kernel 1: Q/K/V projections -> bf16 MFMA layouts, SPLIT precision for Q,K.
//   Qh,Ql,Kh,Kl : [B][N][32] bf16 (hi + RNE residual)
//   Vt          : [B][32][N] bf16 (PV A-operand layout)
// grid (NT, B, 3); block 256 = 4 waves; wave g computes rows 8g..8g+7.
// unroll 8 -> ~16 x-loads in flight (kernel is latency-bound at 2.3 w/SIMD).
// ---------------------------------------------------------------------------
__global__ __launch_bounds__(256) void qkv_kernel(
    const float* __restrict__ x, const float* __restrict__ qw,
    const float* __restrict__ kw, const float* __restrict__ vw,
    ushort_t* __restrict__ Qh, ushort_t* __restrict__ Ql,
    ushort_t* __restrict__ Kh, ushort_t* __restrict__ Kl,
    ushort_t* __restrict__ Vt)
{
    const int b   = blockIdx.y;
    const int z   = blockIdx.z;
    const int nl  = threadIdx.x & 63;
    const int n   = blockIdx.x * 64 + nl;
    const int g   = __builtin_amdgcn_readfirstlane(threadIdx.x >> 6); // 0..3
    const float* w  = (z == 0) ? qw : (z == 1) ? kw : vw;
    const float* xb = x + (size_t)b * CIN * NPOS + n;

    float acc[8];
#pragma unroll
    for (int i = 0; i < 8; ++i) acc[i] = 0.f;
#pragma unroll 8
    for (int c = 0; c < CIN; ++c) {
        float xv = xb[(size_t)c * NPOS];
#pragma unroll
        for (int i = 0; i < 8; ++i)
            acc[i] += w[(g * 8 + i) * CIN + c] * xv;   // wave-uniform -> smem
    }
    if (z == 2) {                                // V -> transposed [32][N]
#pragma unroll
        for (int i = 0; i < 8; ++i)
            Vt[((size_t)b * CR + g * 8 + i) * NPOS + n] = f2bf(acc[i]);
    } else {
        ushort_t* dh = (z == 0) ? Qh : Kh;
        ushort_t* dl = (z == 0) ? Ql : Kl;
        float s = (z == 0) ? QS2 : 1.0f;         // fold softmax scale into Q
        bf16x8s fh, fl;
#pragma unroll
        for (int i = 0; i < 8; ++i) {
            float v = acc[i] * s;
            ushort_t h = f2bf(v);
            fh[i] = (short)h;
            fl[i] = (short)f2bf(v - bf2f(h));    // residual
        }
        size_t off = ((size_t)b * NPOS + n) * CR + g * 8;
        *(bf16x8s*)(dh + off) = fh;
        *(bf16x8s*)(dl + off) = fl;
    }
}

// ---------------------------------------------------------------------------
// Kernel 2: MFMA flash attention, TRANSPOSED scores (S^T = K·Q^T).
// grid (196, S, B); block 64 = 1 wave owning 32 queries (2 q-halves).
// S^T C-layout: row=key (quad*4+r = 4 CONSECUTIVE keys/lane), col=query.
//  -> softmax state (m,l) is lane-resident (q=col), alpha lane-uniform;
//  -> P^T store = 1 packed ds_write_b64 per (h,frag)  [was 128 scalar b16s];
//  -> PV is O^T = V^T (A) · P^T (B, straight ds_read_b128 from LDS);
//  -> O^T layout == Opart[ch][n]: epilogue transpose deleted.
// ---------------------------------------------------------------------------
__global__ __launch_bounds__(64, 4) void attn_kernel(
    const ushort_t* __restrict__ Qh, const ushort_t* __restrict__ Ql,
    const ushort_t* __restrict__ Kh, const ushort_t* __restrict__ Kl,
    const ushort_t* __restrict__ Vt, ushort_t* __restrict__ Opart,
    float* __restrict__ Mp, float* __restrict__ Lp, int iters)
{
    __shared__ __align__(16) ushort_t pbuf[2 * 16 * PPITCH];  // P^T [h][q][72]

    const int lane = threadIdx.x;
    const int col  = lane & 15;                  // query (local) / A-row
    const int quad = lane >> 4;                  // 0..3
    const int b    = blockIdx.z;
    const int s    = blockIdx.y;
    const int qw0  = blockIdx.x * 32;

    const ushort_t* Qhb = Qh + (size_t)b * NPOS * CR;
    const ushort_t* Qlb = Ql + (size_t)b * NPOS * CR;
    const ushort_t* Khb = Kh + (size_t)b * NPOS * CR;
    const ushort_t* Klb = Kl + (size_t)b * NPOS * CR;
    const ushort_t* Vtb = Vt + (size_t)b * CR * NPOS;

    // Q as B-operand (n=q=col, k=ch=quad*8+j) — identical loads to before.
    bf16x8s qbh[2], qbl[2];
    qbh[0] = *(const bf16x8s*)(Qhb + (size_t)(qw0 + col) * CR + quad * 8);
    qbh[1] = *(const bf16x8s*)(Qhb + (size_t)(qw0 + 16 + col) * CR + quad * 8);
    qbl[0] = *(const bf16x8s*)(Qlb + (size_t)(qw0 + col) * CR + quad * 8);
    qbl[1] = *(const bf16x8s*)(Qlb + (size_t)(qw0 + 16 + col) * CR + quad * 8);

    f32x4 oc[2][2];   // O^T frag [h][c]: ch=c*16+quad*4+r, q=qw0+h*16+col
#pragma unroll
    for (int h = 0; h < 2; ++h)
#pragma unroll
        for (int c = 0; c < 2; ++c)
#pragma unroll
            for (int r = 0; r < 4; ++r) oc[h][c][r] = 0.f;
    float m_[2] = { -1e30f, -1e30f };
    float l_[2] = { 0.f, 0.f };                  // per-lane partial

    for (int it = 0; it < iters; ++it) {
        const int j0 = (s * iters + it) * 64;
        // K as A-operand (m=key=col per 16-key frag, k=ch) — same loads.
        bf16x8s kh[4], kl[4], vb[2][2];
#pragma unroll
        for (int f = 0; f < 4; ++f) {
            kh[f] = *(const bf16x8s*)(Khb + (size_t)(j0 + f * 16 + col) * CR + quad * 8);
            kl[f] = *(const bf16x8s*)(Klb + (size_t)(j0 + f * 16 + col) * CR + quad * 8);
        }
        // V^T as A-operand (m=ch=col, k=key=quad*8+j) — same loads.
#pragma unroll
        for (int k2 = 0; k2 < 2; ++k2)
#pragma unroll
            for (int c = 0; c < 2; ++c)
                vb[k2][c] = *(const bf16x8s*)(Vtb + (size_t)(c * 16 + col) * NPOS
                                              + j0 + k2 * 32 + quad * 8);

        f32x4 z4; z4[0] = 0.f; z4[1] = 0.f; z4[2] = 0.f; z4[3] = 0.f;
#pragma unroll
        for (int h = 0; h < 2; ++h) {
            f32x4 sc[4];                         // S^T: key=f*16+quad*4+r, q=col
#pragma unroll
            for (int f = 0; f < 4; ++f) {
                sc[f] = __builtin_amdgcn_mfma_f32_16x16x32_bf16(kl[f], qbh[h], z4, 0, 0, 0);
                sc[f] = __builtin_amdgcn_mfma_f32_16x16x32_bf16(kh[f], qbl[h], sc[f], 0, 0, 0);
                sc[f] = __builtin_amdgcn_mfma_f32_16x16x32_bf16(kh[f], qbh[h], sc[f], 0, 0, 0);
            }
            // max over this lane's 16 keys (tree), then across quads.
            float v0 = fmaxf(fmaxf(sc[0][0], sc[0][1]), fmaxf(sc[0][2], sc[0][3]));
            float v1 = fmaxf(fmaxf(sc[1][0], sc[1][1]), fmaxf(sc[1][2], sc[1][3]));
            float v2 = fmaxf(fmaxf(sc[2][0], sc[2][1]), fmaxf(sc[2][2], sc[2][3]));
            float v3 = fmaxf(fmaxf(sc[3][0], sc[3][1]), fmaxf(sc[3][2], sc[3][3]));
            float v  = fmaxf(fmaxf(v0, v1), fmaxf(v2, v3));
            v = fmaxf(v, __shfl_xor(v, 16));
            v = fmaxf(v, __shfl_xor(v, 32));
            float mo = m_[h];
            float mn = fmaxf(mo, v);
            float al = __builtin_amdgcn_exp2f(mo - mn);  // lane-uniform per q
            float lsum = 0.f;
#pragma unroll
            for (int f = 0; f < 4; ++f) {
                float p0 = __builtin_amdgcn_exp2f(sc[f][0] - mn);
                float p1 = __builtin_amdgcn_exp2f(sc[f][1] - mn);
                float p2 = __builtin_amdgcn_exp2f(sc[f][2] - mn);
                float p3 = __builtin_amdgcn_exp2f(sc[f][3] - mn);
                lsum += (p0 + p1) + (p2 + p3);
                short4v pk;
                pk[0] = (short)f2bf(p0); pk[1] = (short)f2bf(p1);
                pk[2] = (short)f2bf(p2); pk[3] = (short)f2bf(p3);
                // 4 consecutive keys -> one b64 write
                *(short4v*)(&pbuf[h * 16 * PPITCH + col * PPITCH + f * 16 + quad * 4]) = pk;
            }
            m_[h] = mn;
            l_[h] = l_[h] * al + lsum;
#pragma unroll
            for (int r = 0; r < 4; ++r) { oc[h][0][r] *= al; oc[h][1][r] *= al; }
        }
        // PV: O^T += V^T · P^T   (P^T B-operand: n=q=col, k=key=quad*8+j)
#pragma unroll
        for (int h = 0; h < 2; ++h) {
#pragma unroll
            for (int k2 = 0; k2 < 2; ++k2) {
                bf16x8s pb = *(const bf16x8s*)(
                    &pbuf[h * 16 * PPITCH + col * PPITCH + k2 * 32 + quad * 8]);
                oc[h][0] = __builtin_amdgcn_mfma_f32_16x16x32_bf16(vb[k2][0], pb, oc[h][0], 0, 0, 0);
                oc[h][1] = __builtin_amdgcn_mfma_f32_16x16x32_bf16(vb[k2][1], pb, oc[h][1], 0, 0, 0);
            }
        }
    }

    // Finish l: reduce per-lane partials across quads (same q = same col).
#pragma unroll
    for (int h = 0; h < 2; ++h) {
        float l = l_[h];
        l += __shfl_xor(l, 16);
        l += __shfl_xor(l, 32);
        l_[h] = l;
    }

    const size_t sb = (size_t)(s * BATCH + b);
    ushort_t* Ob = Opart + sb * CR * NPOS;
#pragma unroll
    for (int h = 0; h < 2; ++h)
#pragma unroll
        for (int c = 0; c < 2; ++c)
#pragma unroll
            for (int r = 0; r < 4; ++r) {
                int ch = c * 16 + quad * 4 + r;
                Ob[(size_t)ch * NPOS + qw0 + h * 16 + col] = f2bf(oc[h][c][r]);
            }
    if (quad == 0) {                             // 16 lanes own the 16 q's
#pragma unroll
        for (int h = 0; h < 2; ++h) {
            Mp[sb * NPOS + qw0 + h * 16 + col] = m_[h];
            Lp[sb * NPOS + qw0 + h * 16 + col] = l_[h];
        }
    }
}

// ---------------------------------------------------------------------------
// Kernel 3: merge key-splits (log-sum-exp) -> Omrg [B][32][N] fp32.
// Templated on S for full unroll. grid (NT, B, 8): wave g handles ch r=z*4+g.
// ---------------------------------------------------------------------------
template <int S_>
__global__ __launch_bounds__(256) void merge_kernel(
    const ushort_t* __restrict__ Opart, const float* __restrict__ Mp,
    const float* __restrict__ Lp, float* __restrict__ Omrg)
{
    const int b  = blockIdx.y;
    const int z  = blockIdx.z;
    const int nl = threadIdx.x & 63;
    const int n  = blockIdx.x * 64 + nl;
    const int g  = __builtin_amdgcn_readfirstlane(threadIdx.x >> 6);
    const int r  = z * 4 + g;

    float mg = -1e30f;
#pragma unroll
    for (int s = 0; s < S_; ++s)
        mg = fmaxf(mg, Mp[(size_t)(s * BATCH + b) * NPOS + n]);
    float lg = 0.f, acc = 0.f;
#pragma unroll
    for (int s = 0; s < S_; ++s) {
        size_t sb = (size_t)(s * BATCH + b);
        float w = __builtin_amdgcn_exp2f(Mp[sb * NPOS + n] - mg);
        lg  += w * Lp[sb * NPOS + n];
        acc += w * bf2f(Opart[(sb * CR + r) * NPOS + n]);   // coalesced
    }
    Omrg[((size_t)b * CR + r) * NPOS + n] = acc / lg;
}

// ---------------------------------------------------------------------------
// Kernel 4: output projection + residual.
// grid (NT, B, 8), block 256: wave g handles 8 channels c in [z*32+8g, +8).
// ---------------------------------------------------------------------------
__global__ __launch_bounds__(256) void proj_kernel(
    const float* __restrict__ Omrg, const float* __restrict__ ow,
    const float* __restrict__ x, float* __restrict__ y)
{
    const int b  = blockIdx.y;
    const int z  = blockIdx.z;
    const int nl = threadIdx.x & 63;
    const int n  = blockIdx.x * 64 + nl;
    const int g  = __builtin_amdgcn_readfirstlane(threadIdx.x >> 6);

    float o[CR];
#pragma unroll
    for (int r = 0; r < CR; ++r)
        o[r] = Omrg[((size_t)b * CR + r) * NPOS + n];

    const float* xb = x + (size_t)b * CIN * NPOS + n;
    float*       yb = y + (size_t)b * CIN * NPOS + n;
    const int c0 = z * 32 + g * 8;
#pragma unroll
    for (int cc = 0; cc < 8; ++cc) {
        int c = c0 + cc;                          // wave-uniform
        float acc = xb[(size_t)c * NPOS];
#pragma unroll
        for (int r = 0; r < CR; ++r) acc += ow[c * CR + r] * o[r];
        yb[(size_t)c * NPOS] = acc;
    }
}

// ---------------------------------------------------------------------------
extern "C" void kernel_launch(void* const* d_in, const int* in_sizes, int n_in,
                              void* d_out, int out_size, void* d_ws, size_t ws_size,
                              hipStream_t stream)
{
    const float* x  = (const float*)d_in[0];
    const float* qw = (const float*)d_in[1];
    const float* kw = (const float*)d_in[2];
    const float* vw = (const float*)d_in[3];
    const float* ow = (const float*)d_in[4];
    float* out = (float*)d_out;

    const size_t qkvN = (size_t)BATCH * CR * NPOS;   // 401,408 elements
    // S must divide 98 (=6272/64) so every split is whole 64-key iters.
    const int s_cand[4] = {14, 7, 2, 1};
    int S = 1;
    for (int i = 0; i < 4; ++i) {
        int Sc = s_cand[i];
        size_t need = 5 * qkvN * sizeof(ushort_t)            // Qh,Ql,Kh,Kl,Vt
                    + qkvN * sizeof(float)                   // Omrg
                    + (size_t)Sc * qkvN * sizeof(ushort_t)   // Opart
                    + 2 * (size_t)Sc * BATCH * NPOS * sizeof(float); // M,L
        if (need <= ws_size) { S = Sc; break; }
    }
    ushort_t* Qh = (ushort_t*)d_ws;
    ushort_t* Ql = Qh + qkvN;
    ushort_t* Kh = Ql + qkvN;
    ushort_t* Kl = Kh + qkvN;
    ushort_t* Vt = Kl + qkvN;
    float* Omrg  = (float*)(Vt + qkvN);
    ushort_t* Op = (ushort_t*)(Omrg + qkvN);
    float* Mp    = (float*)(Op + (size_t)S * qkvN);
    float* Lp    = Mp + (size_t)S * BATCH * NPOS;
    const int iters = NPOS / (S * 64);

    qkv_kernel<<<dim3(NT, BATCH, 3), 256, 0, stream>>>(x, qw, kw, vw,
                                                       Qh, Ql, Kh, Kl, Vt);
    attn_kernel<<<dim3(196, S, BATCH), 64, 0, stream>>>(Qh, Ql, Kh, Kl, Vt,
                                                        Op, Mp, Lp, iters);
    dim3 mg(NT, BATCH, 8);
    switch (S) {
        case 14: merge_kernel<14><<<mg, 256, 0, stream>>>(Op, Mp, Lp, Omrg); break;
        case 7:  merge_kernel<7> <<<mg, 256, 0, stream>>>(Op, Mp, Lp, Omrg); break;
        case 2:  merge_kernel<2> <<<mg, 256, 0, stream>>>(Op, Mp, Lp, Omrg); break;
        default: merge_kernel<1> <<<mg, 256, 0, stream>>>(Op, Mp, Lp, Omrg); break;
    }
    proj_kernel<<<dim3(NT, BATCH, 8), 256, 0, stream>>>(Omrg, ow, x, out);
}